// Round 4
// baseline (643.665 us; speedup 1.0000x reference)
//
#include <hip/hip_runtime.h>

#define N_ROWS 16384
#define N_COLS 4096
#define MARGIN 0.1f
#define BLOCK  256
#define WAVES  4                              // waves per block
#define ITERS  4                              // row-pairs per block
#define ROWS_PER_BLK (2 * ITERS)              // 8 rows per block
#define NBLK   (N_ROWS / ROWS_PER_BLK)        // 2048 (8 blocks/CU @ 32 waves/CU)
#define V4_PER_ROW (N_COLS / 4)               // 1024
#define HALF_V4 (V4_PER_ROW / 2)              // 512 vec4 per half-row
#define KC (HALF_V4 / 64)                     // 8 vec4 per lane per half-row

typedef float vf4 __attribute__((ext_vector_type(4)));
typedef int   vi4 __attribute__((ext_vector_type(4)));

// Half-row waves @ 8 waves/SIMD. Each row is split across a PAIR of waves
// (wave w handles half (w&1) of row-pair (w>>1)); the half-row cossim slice
// is only c[8] = 32 VGPRs, so the whole kernel fits in <=64 VGPRs and
// __launch_bounds__(256,8) holds 32 waves/CU -- 2x the warp pool of the
// previous full-row version, halving every serial compute bubble's exposure.
// Row sum: 6-step wave butterfly + one parity-buffered LDS exchange with the
// partner wave (+1 syncthreads/iter -- measured free in round 1). Plain
// (cached) loads: the nt hint is an unmeasured path, removed.
//
// Correct column contributes exactly MARGIN per row; subtracted once in the
// final reduce: loss = sum/N - MARGIN.
__global__ __launch_bounds__(BLOCK, 8) void
mm_fused_kernel(const float* __restrict__ cossim,
                const int* __restrict__ target,
                float* __restrict__ partials) {
    const vf4* __restrict__ c4 = (const vf4*)cossim;
    const vi4* __restrict__ t4 = (const vi4*)target;
    const int lane = threadIdx.x & 63, wave = threadIdx.x >> 6;
    const int pair = wave >> 1, half = wave & 1;

    __shared__ float s_row_lds[2][WAVES];   // parity-buffered partner exchange
    __shared__ float s_acc[WAVES];

    float acc = 0.0f;
    // vec4 index of this wave's half-row slice for its first row.
    unsigned vbase = (blockIdx.x * ROWS_PER_BLK + pair) * V4_PER_ROW
                   + half * HALF_V4 + lane;

    for (int it = 0; it < ITERS; ++it) {
        // Hold the half-row of cossim in 32 VGPRs.
        vf4 c[KC];
#pragma unroll
        for (int k = 0; k < KC; ++k)
            c[k] = c4[vbase + k * 64];

        // Stream target through a 16-reg buffer; one-hot dot via fmaf.
        float s = 0.0f;
        {
            vi4 t[4];
#pragma unroll
            for (int k = 0; k < 4; ++k) t[k] = t4[vbase + k * 64];
#pragma unroll
            for (int k = 0; k < 4; ++k)
#pragma unroll
                for (int j = 0; j < 4; ++j)
                    s = fmaf((float)t[k][j], c[k][j], s);
        }
        {
            vi4 t[4];
#pragma unroll
            for (int k = 0; k < 4; ++k) t[k] = t4[vbase + (4 + k) * 64];
#pragma unroll
            for (int k = 0; k < 4; ++k)
#pragma unroll
                for (int j = 0; j < 4; ++j)
                    s = fmaf((float)t[k][j], c[4 + k][j], s);
        }

        // Wave butterfly: all lanes hold this half-row's sum.
#pragma unroll
        for (int off = 1; off < 64; off <<= 1)
            s += __shfl_xor(s, off, 64);

        // Combine with partner wave's half (parity LDS slot, 1 sync/iter).
        if (lane == 0) s_row_lds[it & 1][wave] = s;
        __syncthreads();
        const float s_row = s + s_row_lds[it & 1][wave ^ 1];

        const float mc = MARGIN - s_row;
#pragma unroll
        for (int k = 0; k < KC; ++k)
#pragma unroll
            for (int j = 0; j < 4; ++j)
                acc += fmaxf(mc + c[k][j], 0.0f);

        vbase += 2 * V4_PER_ROW;   // advance one row-pair
    }

    // Block-level reduction of the hinge partial.
#pragma unroll
    for (int off = 32; off > 0; off >>= 1)
        acc += __shfl_down(acc, off, 64);
    if (lane == 0) s_acc[wave] = acc;
    __syncthreads();
    if (threadIdx.x == 0)
        partials[blockIdx.x] = s_acc[0] + s_acc[1] + s_acc[2] + s_acc[3];
}

// Final reduce over NBLK partials. loss = sum/N - MARGIN.
__global__ __launch_bounds__(BLOCK) void
mm_reduce_kernel(const float* __restrict__ partials, float* __restrict__ out) {
    const int t = threadIdx.x;
    float acc = 0.0f;
    for (int i = t; i < NBLK; i += BLOCK) acc += partials[i];
#pragma unroll
    for (int off = 32; off > 0; off >>= 1)
        acc += __shfl_down(acc, off, 64);
    __shared__ float s_wave[BLOCK / 64];
    const int lane = t & 63, wave = t >> 6;
    if (lane == 0) s_wave[wave] = acc;
    __syncthreads();
    if (t == 0)
        out[0] = (s_wave[0] + s_wave[1] + s_wave[2] + s_wave[3]) * (1.0f / N_ROWS)
                 - MARGIN;
}

extern "C" void kernel_launch(void* const* d_in, const int* in_sizes, int n_in,
                              void* d_out, int out_size, void* d_ws, size_t ws_size,
                              hipStream_t stream) {
    const float* cossim = (const float*)d_in[0];
    const int*   target = (const int*)d_in[1];
    float* out      = (float*)d_out;
    float* partials = (float*)d_ws;                  // NBLK floats

    mm_fused_kernel<<<NBLK, BLOCK, 0, stream>>>(cossim, target, partials);
    mm_reduce_kernel<<<1, BLOCK, 0, stream>>>(partials, out);
}

// Round 5
// 487.043 us; speedup vs baseline: 1.3216x; 1.3216x over previous
//
#include <hip/hip_runtime.h>

#define N_ROWS 16384
#define N_COLS 4096
#define MARGIN 0.1f
#define BLOCK  256
#define WAVES  4                                   // waves per block
#define ROWS_PER_WAVE 2
#define NBLK (N_ROWS / (WAVES * ROWS_PER_WAVE))    // 2048 blocks (8/CU)
#define V4_PER_ROW (N_COLS / 4)                    // 1024 vec4 per row

typedef float vf4 __attribute__((ext_vector_type(4)));
typedef int   vi4 __attribute__((ext_vector_type(4)));

// Scan-then-stream, zero row residency. Per row (one wave):
//  1) scan target in 2x vi4 chunks with a ballot early-exit: on average
//     ~62% of the target row is read, the rest is never fetched from HBM.
//  2) one broadcast load cossim[row, col] -> s_row.
//  3) stream the cossim row (unroll 8 -> 8 x 16B loads in flight), hinge
//     accumulated into a 4-wide vf4 accumulator (4 independent add chains).
// Nothing is held across phases -> natural VGPR use stays low WITHOUT any
// forced launch_bounds min-waves (round 4 proved forcing causes scratch
// spill: 417 MB of HBM writes). No LDS in the main loop, no syncthreads.
//
// The correct column contributes max(m + s - s, 0) = MARGIN per row; the
// final reduce subtracts it once: loss = sum/N - MARGIN.
__global__ __launch_bounds__(BLOCK) void
mm_fused_kernel(const float* __restrict__ cossim,
                const int* __restrict__ target,
                float* __restrict__ partials) {
    const vf4* __restrict__ c4 = (const vf4*)cossim;
    const vi4* __restrict__ t4 = (const vi4*)target;
    const int lane = threadIdx.x & 63, wave = threadIdx.x >> 6;

    vf4 accv = {0.0f, 0.0f, 0.0f, 0.0f};
#pragma unroll
    for (int r = 0; r < ROWS_PER_WAVE; ++r) {
        const unsigned row = (blockIdx.x * WAVES + wave) * ROWS_PER_WAVE + r;
        const size_t rowv4 = (size_t)row * V4_PER_ROW;

        // --- Phase 1: find the one-hot column (wave-uniform early exit) ---
        int col = 0;
        for (int i = 0; i < V4_PER_ROW / 128; ++i) {      // 8 chunks max
            const vi4 tA = t4[rowv4 + i * 128 + lane];
            const vi4 tB = t4[rowv4 + i * 128 + 64 + lane];
            const int nzA = tA[0] | tA[1] | tA[2] | tA[3];
            const int nzB = tB[0] | tB[1] | tB[2] | tB[3];
            const unsigned long long m = __ballot((nzA | nzB) != 0);
            if (m) {                                      // uniform branch
                int v4i = i * 128 + lane;
                int e;
                if (nzA) {
                    e = tA[0] ? 0 : tA[1] ? 1 : tA[2] ? 2 : 3;
                } else {
                    v4i += 64;
                    e = tB[0] ? 0 : tB[1] ? 1 : tB[2] ? 2 : 3;
                }
                const int src = (int)__ffsll(m) - 1;      // lane holding the hit
                col = __shfl(v4i * 4 + e, src, 64);
                break;
            }
        }

        // --- Phase 2: one broadcast load of the correct-column sim ---
        const float s_row = cossim[(size_t)row * N_COLS + col];
        const float mc = MARGIN - s_row;

        // --- Phase 3: stream the cossim row, nothing held ---
#pragma unroll 8
        for (int k = 0; k < V4_PER_ROW / 64; ++k) {       // 16 iters
            const vf4 c = c4[rowv4 + k * 64 + lane];
            accv[0] += fmaxf(mc + c[0], 0.0f);
            accv[1] += fmaxf(mc + c[1], 0.0f);
            accv[2] += fmaxf(mc + c[2], 0.0f);
            accv[3] += fmaxf(mc + c[3], 0.0f);
        }
    }

    float acc = (accv[0] + accv[1]) + (accv[2] + accv[3]);

    // Block-level reduction (only sync in the kernel).
#pragma unroll
    for (int off = 32; off > 0; off >>= 1)
        acc += __shfl_down(acc, off, 64);
    __shared__ float s_acc[WAVES];
    if (lane == 0) s_acc[wave] = acc;
    __syncthreads();
    if (threadIdx.x == 0)
        partials[blockIdx.x] = s_acc[0] + s_acc[1] + s_acc[2] + s_acc[3];
}

// Final reduce over NBLK partials. loss = sum/N - MARGIN.
__global__ __launch_bounds__(BLOCK) void
mm_reduce_kernel(const float* __restrict__ partials, float* __restrict__ out) {
    const int t = threadIdx.x;
    float acc = 0.0f;
    for (int i = t; i < NBLK; i += BLOCK) acc += partials[i];
#pragma unroll
    for (int off = 32; off > 0; off >>= 1)
        acc += __shfl_down(acc, off, 64);
    __shared__ float s_wave[BLOCK / 64];
    const int lane = t & 63, wave = t >> 6;
    if (lane == 0) s_wave[wave] = acc;
    __syncthreads();
    if (t == 0)
        out[0] = (s_wave[0] + s_wave[1] + s_wave[2] + s_wave[3]) * (1.0f / N_ROWS)
                 - MARGIN;
}

extern "C" void kernel_launch(void* const* d_in, const int* in_sizes, int n_in,
                              void* d_out, int out_size, void* d_ws, size_t ws_size,
                              hipStream_t stream) {
    const float* cossim = (const float*)d_in[0];
    const int*   target = (const int*)d_in[1];
    float* out      = (float*)d_out;
    float* partials = (float*)d_ws;                  // NBLK floats

    mm_fused_kernel<<<NBLK, BLOCK, 0, stream>>>(cossim, target, partials);
    mm_reduce_kernel<<<1, BLOCK, 0, stream>>>(partials, out);
}